// Round 1
// baseline (155.926 us; speedup 1.0000x reference)
//
#include <hip/hip_runtime.h>
#include <hip/hip_fp16.h>

#define NEGF (-60000.0f)   // finite "log 0": exp underflows to 0, never produces NaN

constexpr int B = 8, T = 128, U = 64, U1 = 65, V = 512;
constexpr int SROW = 66;   // padded row stride for blank/lab: anti-diag delta = -65 == -1 mod 32 banks

// workspace layout (float units)
constexpr int ET_F = 0;                    // exp(trans - mt): B*T*V
constexpr int EP_F = ET_F + B * T * V;     // exp(pred - mp): B*U1*V
constexpr int MT_F = EP_F + B * U1 * V;    // row max of trans: B*T
constexpr int MP_F = MT_F + B * T;         // row max of pred:  B*U1
constexpr int HL_F = MP_F + B * U1;        // 792072, %4==0 -> 16B aligned byte offset
// half region: per b: blank[T*SROW] then lab[T*SROW]
constexpr int HB_PER_B = 2 * T * SROW;     // 16896 halves = 33792 bytes per b

// ---------------- k1: row maxes + exp, and zero the output accumulator ----------------
__global__ __launch_bounds__(256) void k_exp_rows(const float* __restrict__ trans,
                                                  const float* __restrict__ pred,
                                                  float* __restrict__ ws,
                                                  float* __restrict__ out) {
    if (blockIdx.x == 0 && threadIdx.x == 0) out[0] = 0.0f;
    const int wave = (blockIdx.x * blockDim.x + threadIdx.x) >> 6;
    const int lane = threadIdx.x & 63;
    const int nrows_t = B * T;            // 1024 trans rows
    const int nrows = nrows_t + B * U1;   // + 520 pred rows
    if (wave >= nrows) return;

    const float* src;
    float* dst;
    float* mdst;
    if (wave < nrows_t) {
        src = trans + (size_t)wave * V;
        dst = ws + ET_F + (size_t)wave * V;
        mdst = ws + MT_F + wave;
    } else {
        int r = wave - nrows_t;
        src = pred + (size_t)r * V;
        dst = ws + EP_F + (size_t)r * V;
        mdst = ws + MP_F + r;
    }
    // 512 floats = 128 float4; lane reads idx lane and lane+64 (coalesced)
    float4 a = ((const float4*)src)[lane];
    float4 c = ((const float4*)src)[lane + 64];
    float m = fmaxf(fmaxf(fmaxf(a.x, a.y), fmaxf(a.z, a.w)),
                    fmaxf(fmaxf(c.x, c.y), fmaxf(c.z, c.w)));
    #pragma unroll
    for (int off = 32; off >= 1; off >>= 1) m = fmaxf(m, __shfl_xor(m, off));

    float4 r0 = make_float4(__expf(a.x - m), __expf(a.y - m), __expf(a.z - m), __expf(a.w - m));
    float4 r1 = make_float4(__expf(c.x - m), __expf(c.y - m), __expf(c.z - m), __expf(c.w - m));
    ((float4*)dst)[lane]      = r0;
    ((float4*)dst)[lane + 64] = r1;
    if (lane == 0) *mdst = m;
}

// ---------------- k2: batched dot GEMM + blank/lab epilogue ----------------
// grid (5 u-tiles, 8 t-tiles, 8 b), block (16,16). Each thread: one (t,u) dot of length 512.
__global__ __launch_bounds__(256) void k_gemm(const float* __restrict__ trans,
                                              const float* __restrict__ pred,
                                              const int* __restrict__ labels,
                                              const int* __restrict__ label_lens,
                                              float* __restrict__ ws) {
    const int b  = blockIdx.z;
    const int t0 = blockIdx.y * 16;
    const int u0 = blockIdx.x * 16;
    const int tx = threadIdx.x, ty = threadIdx.y;

    __shared__ float Et[16][33];
    __shared__ float Ep[16][33];

    const float* et = ws + ET_F + ((size_t)b * T + t0) * V;
    const float* ep = ws + EP_F + (size_t)b * U1 * V;

    const int tid  = ty * 16 + tx;
    const int lrow = tid >> 4;        // 0..15
    const int lcol = (tid & 15) * 2;  // 0..30
    int urow = u0 + lrow; if (urow > U1 - 1) urow = U1 - 1;  // clamp (pad tile)

    float acc = 0.0f;
    for (int kc = 0; kc < V; kc += 32) {
        float2 ea = *(const float2*)(et + (size_t)lrow * V + kc + lcol);
        float2 eb = *(const float2*)(ep + (size_t)urow * V + kc + lcol);
        __syncthreads();
        Et[lrow][lcol] = ea.x; Et[lrow][lcol + 1] = ea.y;
        Ep[lrow][lcol] = eb.x; Ep[lrow][lcol + 1] = eb.y;
        __syncthreads();
        #pragma unroll
        for (int k = 0; k < 32; ++k)
            acc += Et[ty][k] * Ep[tx][k];
    }

    const int t = t0 + ty, u = u0 + tx;
    if (u >= U1) return;

    const float mt = ws[MT_F + b * T + t];
    const float mp = ws[MP_F + b * U1 + u];
    const float lse = mt + mp + __logf(acc);

    __half* hb = (__half*)(ws + HL_F) + (size_t)b * HB_PER_B;
    const float tr0 = trans[((size_t)b * T + t) * V];
    const float pr0 = pred[((size_t)b * U1 + u) * V];
    hb[t * SROW + u] = __float2half(tr0 + pr0 - lse);   // blank_lp

    if (u < U) {
        float lv;
        if (u >= label_lens[b]) {
            lv = NEGF;
        } else {
            const int l = labels[(size_t)b * U + u];
            lv = trans[((size_t)b * T + t) * V + l] + pred[((size_t)b * U1 + u) * V + l] - lse;
        }
        hb[T * SROW + t * SROW + u] = __float2half(lv); // lab_lp
    }
}

// ---------------- k3: anti-diagonal alpha DP, one wave per batch element ----------------
__global__ __launch_bounds__(64) void k_dp(const float* __restrict__ ws,
                                           const int* __restrict__ act_lens,
                                           const int* __restrict__ label_lens,
                                           float* __restrict__ out) {
    const int b = blockIdx.x;
    const int lane = threadIdx.x;

    __shared__ uint4 smv[(2 * T * SROW) / 8];  // 16896 halves = 2112 uint4
    const uint4* src = (const uint4*)((const char*)ws + (size_t)HL_F * 4 + (size_t)b * (HB_PER_B * 2));
    for (int i = lane; i < (2 * T * SROW) / 8; i += 64) smv[i] = src[i];
    __syncthreads();
    const __half* blank = (const __half*)smv;            // [t*SROW + u], u in [0,65)
    const __half* lab   = (const __half*)smv + T * SROW; // [t*SROW + u], u in [0,64)

    const int tl = act_lens[b] - 1;     // >= 63
    const int ul = label_lens[b];       // in [32, 64]

    float cur = 0.0f;    // lane u holds alpha[t][u] along its anti-diagonal sweep
    float cur64 = 0.0f;  // lane 63 additionally owns u = 64
    float ll = 0.0f;
    bool have = false;

    for (int d = 1; d <= T - 1 + U; ++d) {   // 191 diagonals
        const float left = __shfl_up(cur, 1);   // alpha[t][u-1] from lane u-1 (prev diag)

        if (lane == 63) {  // u = 64 cell, t64 = d - 64; uses pre-update cur = alpha[t64][63]
            const int t64 = d - 64;
            if (t64 == 0) {
                cur64 = cur + __half2float(lab[63]);
            } else if (t64 >= 1 && t64 < T) {
                const float a1 = cur64 + __half2float(blank[(t64 - 1) * SROW + 64]);
                const float a2 = cur + __half2float(lab[t64 * SROW + 63]);
                const float m = fmaxf(a1, a2);
                cur64 = m + __logf(__expf(a1 - m) + __expf(a2 - m));
            }
            if (ul == 64 && t64 == tl) { ll = cur64 + __half2float(blank[tl * SROW + 64]); have = true; }
        }

        const int t = d - lane;
        if (t >= 1 && t < T) {
            const float a1 = cur + __half2float(blank[(t - 1) * SROW + lane]);
            if (lane == 0) {
                cur = a1;
            } else {
                const float a2 = left + __half2float(lab[t * SROW + lane - 1]);
                const float m = fmaxf(a1, a2);
                cur = m + __logf(__expf(a1 - m) + __expf(a2 - m));
            }
        } else if (t == 0) {   // lane >= 1 here; t=0 row is a cumsum of lab
            cur = left + __half2float(lab[lane - 1]);
        }

        if (lane == ul && d - lane == tl) { ll = cur + __half2float(blank[tl * SROW + lane]); have = true; }
    }

    if (have) atomicAdd(out, -ll);
}

extern "C" void kernel_launch(void* const* d_in, const int* in_sizes, int n_in,
                              void* d_out, int out_size, void* d_ws, size_t ws_size,
                              hipStream_t stream) {
    const float* trans      = (const float*)d_in[0];
    const float* pred       = (const float*)d_in[1];
    const int*   labels     = (const int*)d_in[2];
    const int*   act_lens   = (const int*)d_in[3];
    const int*   label_lens = (const int*)d_in[4];
    float* ws  = (float*)d_ws;
    float* out = (float*)d_out;

    const int nrows = B * T + B * U1;                 // 1544 rows, 4 waves/block
    k_exp_rows<<<(nrows + 3) / 4, 256, 0, stream>>>(trans, pred, ws, out);
    k_gemm<<<dim3(5, 8, 8), dim3(16, 16), 0, stream>>>(trans, pred, labels, label_lens, ws);
    k_dp<<<8, 64, 0, stream>>>(ws, act_lens, label_lens, out);
}

// Round 2
// 106.995 us; speedup vs baseline: 1.4573x; 1.4573x over previous
//
#include <hip/hip_runtime.h>
#include <hip/hip_fp16.h>

// log2-domain "log 0": must survive half round-trip (half max 65504) and never
// reach fmax as NaN. exp2(-30000) == 0 exactly.
#define NEG2 (-30000.0f)
#define L2E  1.4426950408889634f
#define LN2  0.6931471805599453f

constexpr int B = 8, T = 128, U = 64, U1 = 65, V = 512;

// workspace layout (float units)
constexpr int ET_F = 0;                    // exp(trans - mt): B*T*V
constexpr int EP_F = ET_F + B * T * V;     // exp(pred - mp): B*U1*V
constexpr int MT_F = EP_F + B * U1 * V;    // row max of trans: B*T
constexpr int MP_F = MT_F + B * T;         // row max of pred:  B*U1
constexpr int C0_F = MP_F + B * U1;        // blank~[t][0] column (log2 dom, f32): B*T
constexpr int P_F  = C0_F + B * T;         // packed half2 lattice, per b: 129*64 words
constexpr int PW   = 129 * 64;             // words per b; P[t][l] = half2(blank~[t-1][l+1], lab~[t][l])

// ---------------- DPP helpers ----------------
__device__ __forceinline__ float wave_shr1(float x) {   // lane i <- lane i-1 (lane0 garbage, caller selects)
    int v = __float_as_int(x);
    int r = __builtin_amdgcn_update_dpp(v, v, 0x138, 0xF, 0xF, false); // wave_shr:1
    return __int_as_float(r);
}

__device__ __forceinline__ float wave_sum(float x) {    // full-wave sum, broadcast to all lanes
    int v;
    v = __float_as_int(x);
    x += __int_as_float(__builtin_amdgcn_update_dpp(0, v, 0x111, 0xF, 0xF, true)); // row_shr:1
    v = __float_as_int(x);
    x += __int_as_float(__builtin_amdgcn_update_dpp(0, v, 0x112, 0xF, 0xF, true)); // row_shr:2
    v = __float_as_int(x);
    x += __int_as_float(__builtin_amdgcn_update_dpp(0, v, 0x114, 0xF, 0xF, true)); // row_shr:4
    v = __float_as_int(x);
    x += __int_as_float(__builtin_amdgcn_update_dpp(0, v, 0x118, 0xF, 0xF, true)); // row_shr:8
    v = __float_as_int(x);
    x += __int_as_float(__builtin_amdgcn_update_dpp(0, v, 0x142, 0xA, 0xF, true)); // row_bcast:15
    v = __float_as_int(x);
    x += __int_as_float(__builtin_amdgcn_update_dpp(0, v, 0x143, 0xC, 0xF, true)); // row_bcast:31
    return __int_as_float(__builtin_amdgcn_readlane(__float_as_int(x), 63));
}

// ---------------- k1: row maxes + exp, zero the output ----------------
__global__ __launch_bounds__(256) void k_exp_rows(const float* __restrict__ trans,
                                                  const float* __restrict__ pred,
                                                  float* __restrict__ ws,
                                                  float* __restrict__ out) {
    if (blockIdx.x == 0 && threadIdx.x == 0) out[0] = 0.0f;
    const int wave = (blockIdx.x * blockDim.x + threadIdx.x) >> 6;
    const int lane = threadIdx.x & 63;
    const int nrows_t = B * T;
    const int nrows = nrows_t + B * U1;
    if (wave >= nrows) return;

    const float* src; float* dst; float* mdst;
    if (wave < nrows_t) {
        src = trans + (size_t)wave * V;
        dst = ws + ET_F + (size_t)wave * V;
        mdst = ws + MT_F + wave;
    } else {
        int r = wave - nrows_t;
        src = pred + (size_t)r * V;
        dst = ws + EP_F + (size_t)r * V;
        mdst = ws + MP_F + r;
    }
    float4 a = ((const float4*)src)[lane];
    float4 c = ((const float4*)src)[lane + 64];
    float m = fmaxf(fmaxf(fmaxf(a.x, a.y), fmaxf(a.z, a.w)),
                    fmaxf(fmaxf(c.x, c.y), fmaxf(c.z, c.w)));
    #pragma unroll
    for (int off = 32; off >= 1; off >>= 1) m = fmaxf(m, __shfl_xor(m, off));

    float4 r0 = make_float4(__expf(a.x - m), __expf(a.y - m), __expf(a.z - m), __expf(a.w - m));
    float4 r1 = make_float4(__expf(c.x - m), __expf(c.y - m), __expf(c.z - m), __expf(c.w - m));
    ((float4*)dst)[lane]      = r0;
    ((float4*)dst)[lane + 64] = r1;
    if (lane == 0) *mdst = m;
}

// ---------------- k2: wave-per-(b,t) row dot + packed epilogue ----------------
// grid 256 x 256 threads = 1024 waves = B*T rows. Lane holds ET[t][lane*8..+8] in regs;
// loops u streaming EP rows; DPP wave reduction; lane-parallel epilogue writes P/C0.
__global__ __launch_bounds__(256) void k_dot(const float* __restrict__ trans,
                                             const float* __restrict__ pred,
                                             const int* __restrict__ labels,
                                             const int* __restrict__ label_lens,
                                             float* __restrict__ ws) {
    const int lane = threadIdx.x & 63;
    const int row  = blockIdx.x * 4 + (threadIdx.x >> 6);  // 0..1023
    const int b = row >> 7, t = row & 127;

    const float4* et4 = (const float4*)(ws + ET_F + (size_t)row * V);
    const float4 ea = et4[lane * 2], eb = et4[lane * 2 + 1];
    const float mt = ws[MT_F + row];

    const float4* ep4 = (const float4*)(ws + EP_F + (size_t)b * U1 * V);

    float mysum = 1.0f;   // lane u keeps sum for u == lane
    float sum64 = 1.0f;
    float4 pa = ep4[lane * 2], pb = ep4[lane * 2 + 1];
    for (int u = 0; u < U1; ++u) {
        const int un = (u + 1 < U1) ? u + 1 : U1 - 1;
        float4 na = ep4[un * (V / 4) + lane * 2];
        float4 nb = ep4[un * (V / 4) + lane * 2 + 1];
        float s = ea.x * pa.x + ea.y * pa.y + ea.z * pa.z + ea.w * pa.w
                + eb.x * pb.x + eb.y * pb.y + eb.z * pb.z + eb.w * pb.w;
        const float tot = wave_sum(s);
        mysum = (lane == u) ? tot : mysum;
        if (u == 64) sum64 = tot;   // uniform
        pa = na; pb = nb;
    }

    // ---- epilogue: lane == u (0..63); lane 63 additionally handles u=64 ----
    const int u = lane;
    const int ul = label_lens[b];
    const float mp_u = ws[MP_F + b * U1 + u];
    const float pr0  = pred[((size_t)b * U1 + u) * V];
    const float tr0  = trans[(size_t)row * V];
    const float lse2 = (mt + mp_u) * L2E + __log2f(mysum);   // log2-domain lse

    __half* Pb = (__half*)(ws + P_F + (size_t)b * PW);
    const float bl2 = (tr0 + pr0) * L2E - lse2;              // blank~[t][u]
    if (u >= 1) Pb[((t + 1) * 64 + (u - 1)) * 2] = __float2half(bl2);
    else        ws[C0_F + row] = bl2;                        // u==0 column, f32

    float lb2;
    if (u >= ul) lb2 = NEG2;
    else {
        const int lbl = labels[b * U + u];
        lb2 = (trans[(size_t)row * V + lbl] + pred[((size_t)b * U1 + u) * V + lbl]) * L2E - lse2;
    }
    Pb[(t * 64 + u) * 2 + 1] = __float2half(lb2);            // lab~[t][u]

    if (lane == 63) {                                        // u = 64 blank
        const float mp64 = ws[MP_F + b * U1 + 64];
        const float p64  = pred[((size_t)b * U1 + 64) * V];
        const float l2   = (mt + mp64) * L2E + __log2f(sum64);
        Pb[((t + 1) * 64 + 63) * 2] = __float2half((tr0 + p64) * L2E - l2);
    }
}

// ---------------- k3: anti-diagonal DP, one wave per b, branchless + DPP + prefetch ----------------
__global__ __launch_bounds__(64) void k_dp(const float* __restrict__ ws,
                                           const int* __restrict__ act_lens,
                                           const int* __restrict__ label_lens,
                                           float* __restrict__ out) {
    const int b = blockIdx.x, l = threadIdx.x;

    __shared__ uint4 Pv[PW / 4];   // 2064 uint4 = 33 KB
    __shared__ float af[T];        // alpha[t][0] column (log2 dom)

    const uint4* src = (const uint4*)(ws + P_F + (size_t)b * PW);
    #pragma unroll
    for (int i = 0; i < 33; ++i) {
        const int idx = l + i * 64;
        if (idx < PW / 4) Pv[idx] = src[idx];
    }

    // alpha0 column: inclusive prefix scan of C0 (128 values, 2 per lane)
    const float* c0 = ws + C0_F + b * T;
    float x0 = c0[l], x1 = c0[64 + l];
    #pragma unroll
    for (int off = 1; off < 64; off <<= 1) { float y = __shfl_up(x0, off); if (l >= off) x0 += y; }
    #pragma unroll
    for (int off = 1; off < 64; off <<= 1) { float y = __shfl_up(x1, off); if (l >= off) x1 += y; }
    const float tot = __shfl(x0, 63);
    if (l == 0) af[0] = 0.0f;
    af[l + 1] = x0;                    // t = 1..64
    if (l < 63) af[65 + l] = tot + x1; // t = 65..127
    __syncthreads();

    const uint* Pw = (const uint*)Pv;
    const int tl = act_lens[b] - 1;    // >= 63
    const int ul = label_lens[b];      // in [32, 64]
    const int dmax = tl + ul;

    // lane l owns u = l+1; at step d: t = d - l - 1; P word (clamped) holds both operands
    auto paddr = [&](int d) -> int {
        int t = d - l - 1;
        int tc = min(max(t, 0), 128);
        return tc * 64 + l;
    };

    uint  w0 = Pw[paddr(1)], w1 = Pw[paddr(2)];
    float a00 = af[0],       a01 = af[1];
    float cur = 0.0f;

    for (int d = 1; d <= dmax; ++d) {
        // prefetch step d+2
        const uint  w2  = Pw[paddr(d + 2)];
        const float a02 = af[min(d + 1, T - 1)];

        const int t = d - l - 1;
        union { uint u; __half2 h; } cv; cv.u = w0;
        const float bn = __half2float(cv.h.x);   // blank~[t-1][u]
        const float lb = __half2float(cv.h.y);   // lab~[t][u-1]

        const float sh = wave_shr1(cur);
        const float lv = (l == 0) ? a00 : sh;    // alpha[t][u-1]
        const float a2 = lv + lb;
        const float a1 = (t >= 1) ? cur + bn : NEG2;
        const float m  = fmaxf(a1, a2);
        const float nc = m + __log2f(exp2f(a1 - m) + exp2f(a2 - m));
        const bool valid = (t >= 0) && (t <= tl);
        cur = valid ? nc : cur;

        w0 = w1; w1 = w2; a00 = a01; a01 = a02;
    }

    if (l == ul - 1) {
        union { uint u; __half2 h; } cv; cv.u = Pw[(tl + 1) * 64 + (ul - 1)];
        const float ll = (cur + __half2float(cv.h.x)) * LN2;
        atomicAdd(out, -ll);
    }
}

extern "C" void kernel_launch(void* const* d_in, const int* in_sizes, int n_in,
                              void* d_out, int out_size, void* d_ws, size_t ws_size,
                              hipStream_t stream) {
    const float* trans      = (const float*)d_in[0];
    const float* pred       = (const float*)d_in[1];
    const int*   labels     = (const int*)d_in[2];
    const int*   act_lens   = (const int*)d_in[3];
    const int*   label_lens = (const int*)d_in[4];
    float* ws  = (float*)d_ws;
    float* out = (float*)d_out;

    const int nrows = B * T + B * U1;
    k_exp_rows<<<(nrows + 3) / 4, 256, 0, stream>>>(trans, pred, ws, out);
    k_dot<<<256, 256, 0, stream>>>(trans, pred, labels, label_lens, ws);
    k_dp<<<8, 64, 0, stream>>>(ws, act_lens, label_lens, out);
}